// Round 7
// baseline (99.757 us; speedup 1.0000x reference)
//
#include <hip/hip_runtime.h>

// ScaledDotProductAttention B=8, L=2048, D=64, fp32 in/out.
//
// Two-launch scheme (ws >= 8 MB):
//  1) prepass: K -> fp16 copy (K16), V -> fp16 transposed (VT16) in d_ws.
//  2) attn_bp: grid 512 (8 batch x 64 qblocks of 32 queries), 4 waves/block,
//     wave w owns keys [w*512, w*512+512) in 16 tiles of 32. NO LDS in the
//     hot loop:
//       - QK computed TRANSPOSED: S^T = K·Q^T (A = K rows, B = Q rows; both
//         contiguous half8 loads). C-layout: lane holds P^T[key=quad*4+r][q=l15].
//       - softmax: p = exp2(s) (0.125*log2e folded into Q), one acc/lane for l.
//       - P^T (C-layout) -> P (A-layout) via REGISTER transpose: pack 2 halves
//         per dword, 16 ds_bpermute (__shfl) + 8 selects per 32-key tile.
//         No lgkmcnt FIFO hazard, no barriers -> compiler pipelines freely.
//       - PV: A = P frags, B = VT16 rows (global half8). O accumulates in the
//         same C-layout as the R3 kernel -> proven epilogue reused verbatim.
//     Register double-buffer prefetch of next tile's K/V fragments.
// Fallback: proven R3 kernel if ws too small.

#define B_ 8
#define L_ 2048
#define D_ 64
#define NT 256
#define TK 32              // keys per tile

typedef _Float16 half8_t __attribute__((ext_vector_type(8)));
typedef _Float16 half2v __attribute__((ext_vector_type(2)));
typedef int int4v __attribute__((ext_vector_type(4)));
typedef float f32x4 __attribute__((ext_vector_type(4)));

#define SCALE_LOG2E 0.1803368801111244f   // 0.125 * log2(e)

// ---------------------------------------------------------------- prepass --
// blocks 0..511: K cast; 512..767: V transpose.
__global__ __launch_bounds__(NT) void prepass(
    const float* __restrict__ K, const float* __restrict__ V,
    _Float16* __restrict__ K16, _Float16* __restrict__ VT16)
{
    const int blk = blockIdx.x;
    const int t = threadIdx.x;
    if (blk < 512) {
        const int i = blk * NT + t;                  // half8 index, 131072 total
        const float4* s4 = (const float4*)K;
        const float4 a = s4[2 * i], b = s4[2 * i + 1];
        half8_t w;
        w[0] = (_Float16)a.x; w[1] = (_Float16)a.y;
        w[2] = (_Float16)a.z; w[3] = (_Float16)a.w;
        w[4] = (_Float16)b.x; w[5] = (_Float16)b.y;
        w[6] = (_Float16)b.z; w[7] = (_Float16)b.w;
        ((half8_t*)K16)[i] = w;
    } else {
        __shared__ __align__(16) _Float16 Lt[64 * 72];   // [dim][key] tile
        const int vblk = blk - 512;
        const int bb = vblk >> 5;            // batch
        const int kt = vblk & 31;            // 64-key tile
        const int r  = t >> 2;               // key row 0..63
        const int ch = t & 3;                // 16-dim chunk
        const float* vrow = V + ((size_t)bb * L_ + kt * 64 + r) * D_ + ch * 16;
        #pragma unroll
        for (int i = 0; i < 4; ++i) {
            const float4 f = ((const float4*)vrow)[i];
            const int d0 = ch * 16 + i * 4;
            Lt[(d0 + 0) * 72 + r] = (_Float16)f.x;
            Lt[(d0 + 1) * 72 + r] = (_Float16)f.y;
            Lt[(d0 + 2) * 72 + r] = (_Float16)f.z;
            Lt[(d0 + 3) * 72 + r] = (_Float16)f.w;
        }
        __syncthreads();
        const int d  = t >> 2;               // dim row 0..63
        const int c2 = t & 3;                // 16-key chunk
        const half8_t w0 = *(const half8_t*)&Lt[d * 72 + c2 * 16];
        const half8_t w1 = *(const half8_t*)&Lt[d * 72 + c2 * 16 + 8];
        _Float16* orow = VT16 + ((size_t)bb * D_ + d) * L_ + kt * 64 + c2 * 16;
        *(half8_t*)orow = w0;
        *(half8_t*)(orow + 8) = w1;
    }
}

// -------------------------------------------------------------- main body --

// Load K/V fragments for the 32-key tile at KB.
#define LOADT(KB, BK, BV)                                                       \
    {                                                                           \
        _Pragma("unroll") for (int s = 0; s < 2; ++s)                           \
        _Pragma("unroll") for (int c = 0; c < 2; ++c)                           \
            BK[s][c] = *(const half8_t*)&Kb[(size_t)((KB) + s * 16 + l15) * D_ + c * 32 + quad * 8]; \
        _Pragma("unroll") for (int d = 0; d < 4; ++d)                           \
            BV[d] = *(const half8_t*)&Vb[(size_t)(d * 16 + l15) * L_ + (KB) + quad * 8]; \
    }

// Process one 32-key tile: QK^T (transposed), exp2, register transpose, PV.
#define PROC(BK, BV)                                                            \
    {                                                                           \
        f32x4 sc[2][2];                                                         \
        _Pragma("unroll") for (int ks = 0; ks < 2; ++ks)                        \
        _Pragma("unroll") for (int qs = 0; qs < 2; ++qs) {                      \
            f32x4 acc = (f32x4){0.f, 0.f, 0.f, 0.f};                            \
            acc = __builtin_amdgcn_mfma_f32_16x16x32_f16(BK[ks][0], bq[qs][0], acc, 0, 0, 0); \
            acc = __builtin_amdgcn_mfma_f32_16x16x32_f16(BK[ks][1], bq[qs][1], acc, 0, 0, 0); \
            sc[ks][qs] = acc;                                                   \
        }                                                                       \
        int pk[2][2][2];                                                        \
        _Pragma("unroll") for (int ks = 0; ks < 2; ++ks)                        \
        _Pragma("unroll") for (int qs = 0; qs < 2; ++qs) {                      \
            const float p0 = __builtin_exp2f(sc[ks][qs][0]);                    \
            const float p1 = __builtin_exp2f(sc[ks][qs][1]);                    \
            const float p2 = __builtin_exp2f(sc[ks][qs][2]);                    \
            const float p3 = __builtin_exp2f(sc[ks][qs][3]);                    \
            lacc[qs] += (p0 + p1) + (p2 + p3);                                  \
            half2v h01; h01[0] = (_Float16)p0; h01[1] = (_Float16)p1;           \
            half2v h23; h23[0] = (_Float16)p2; h23[1] = (_Float16)p3;           \
            pk[ks][qs][0] = __builtin_bit_cast(int, h01);                       \
            pk[ks][qs][1] = __builtin_bit_cast(int, h23);                       \
        }                                                                       \
        _Pragma("unroll") for (int qs = 0; qs < 2; ++qs) {                      \
            const int srcA = ((quad & 1) << 5) + l15;                           \
            const int srcB = srcA + 16;                                         \
            const int a0 = __shfl(pk[0][qs][0], srcA, 64);                      \
            const int b0 = __shfl(pk[1][qs][0], srcA, 64);                      \
            const int a1 = __shfl(pk[0][qs][1], srcA, 64);                      \
            const int b1 = __shfl(pk[1][qs][1], srcA, 64);                      \
            const int a2 = __shfl(pk[0][qs][0], srcB, 64);                      \
            const int b2 = __shfl(pk[1][qs][0], srcB, 64);                      \
            const int a3 = __shfl(pk[0][qs][1], srcB, 64);                      \
            const int b3 = __shfl(pk[1][qs][1], srcB, 64);                      \
            const bool hi = quad >= 2;                                          \
            int4v dw;                                                           \
            dw[0] = hi ? b0 : a0; dw[1] = hi ? b1 : a1;                         \
            dw[2] = hi ? b2 : a2; dw[3] = hi ? b3 : a3;                         \
            const half8_t ap = __builtin_bit_cast(half8_t, dw);                 \
            _Pragma("unroll") for (int d = 0; d < 4; ++d)                       \
                ofr[qs][d] = __builtin_amdgcn_mfma_f32_16x16x32_f16(ap, BV[d], ofr[qs][d], 0, 0, 0); \
        }                                                                       \
    }

__global__ __launch_bounds__(NT) void attn_bp(
    const float* __restrict__ Q,
    const _Float16* __restrict__ K16,
    const _Float16* __restrict__ VT16,
    float* __restrict__ O)
{
    __shared__ float Ored[256 * 33];                     // 33792 B (epilogue only)
    __shared__ float Lred[128];                          // 512 B

    const int t    = threadIdx.x;
    const int wave = t >> 6;
    const int lane = t & 63;
    const int quad = lane >> 4;
    const int l15  = lane & 15;

    const int b   = blockIdx.x & 7;            // batch <-> XCD affinity
    const int qbi = blockIdx.x >> 3;           // query block 0..63
    const int qb  = qbi * 32;
    const int key0 = wave * (TK * 16);         // wave's 512-key range

    const _Float16* Kb = K16 + (size_t)b * L_ * D_;
    const _Float16* Vb = VT16 + (size_t)b * D_ * L_;

    // ---- Q B-frags from fp32, pre-scaled by 0.125*log2(e) ----
    // B[k-dim=quad*8+j][n=q=l15] = Q[qb+qs*16+l15][c*32+quad*8+j] (contiguous)
    half8_t bq[2][2];
    #pragma unroll
    for (int qs = 0; qs < 2; ++qs) {
        const float* qp = Q + ((size_t)b * L_ + qb + qs * 16 + l15) * D_ + quad * 8;
        #pragma unroll
        for (int c = 0; c < 2; ++c) {
            const float4 f0 = *(const float4*)(qp + c * 32);
            const float4 f1 = *(const float4*)(qp + c * 32 + 4);
            bq[qs][c][0] = (_Float16)(f0.x * SCALE_LOG2E);
            bq[qs][c][1] = (_Float16)(f0.y * SCALE_LOG2E);
            bq[qs][c][2] = (_Float16)(f0.z * SCALE_LOG2E);
            bq[qs][c][3] = (_Float16)(f0.w * SCALE_LOG2E);
            bq[qs][c][4] = (_Float16)(f1.x * SCALE_LOG2E);
            bq[qs][c][5] = (_Float16)(f1.y * SCALE_LOG2E);
            bq[qs][c][6] = (_Float16)(f1.z * SCALE_LOG2E);
            bq[qs][c][7] = (_Float16)(f1.w * SCALE_LOG2E);
        }
    }

    f32x4 ofr[2][4];
    #pragma unroll
    for (int qs = 0; qs < 2; ++qs)
        #pragma unroll
        for (int d = 0; d < 4; ++d)
            ofr[qs][d] = (f32x4){0.f, 0.f, 0.f, 0.f};
    float lacc[2] = {0.f, 0.f};

    // ---- hot loop: 16 tiles, register double-buffered, zero LDS ----
    half8_t bkA[2][2], bvA[4], bkB[2][2], bvB[4];
    LOADT(key0, bkA, bvA);
    for (int it = 0; it < 8; ++it) {
        const int kb = key0 + it * 64;
        LOADT(kb + 32, bkB, bvB);
        PROC(bkA, bvA);
        // last iteration prefetches 32 keys past the wave's range: stays
        // inside K16/VT16/ws mapping (see launch: ws >= 8 MB) and is unused.
        LOADT(kb + 64, bkA, bvA);
        PROC(bkB, bvB);
    }

    // ---- reduce l over quads (p for query qs*16+l15 lives on 4 quads) ----
    #pragma unroll
    for (int qs = 0; qs < 2; ++qs) {
        float v = lacc[qs];
        v += __shfl_xor(v, 16, 64);
        v += __shfl_xor(v, 32, 64);
        lacc[qs] = v;
    }
    if (quad == 0) {
        Lred[wave * 32 + l15] = lacc[0];
        Lred[wave * 32 + 16 + l15] = lacc[1];
    }

    // ---- cross-wave combine (waves own disjoint keys) ----
    #pragma unroll
    for (int qs = 0; qs < 2; ++qs)
        #pragma unroll
        for (int d = 0; d < 4; ++d)
            #pragma unroll
            for (int r = 0; r < 4; ++r)
                Ored[(wave * 64 + lane) * 33 + qs * 16 + d * 4 + r] = ofr[qs][d][r];
    __syncthreads();

    #pragma unroll
    for (int qs = 0; qs < 2; ++qs)
        #pragma unroll
        for (int r = 0; r < 4; ++r) {
            float osum = 0.f;
            #pragma unroll
            for (int w2 = 0; w2 < 4; ++w2)
                osum += Ored[(w2 * 64 + lane) * 33 + qs * 16 + wave * 4 + r];
            const int row = qs * 16 + quad * 4 + r;
            const float lt = Lred[row] + Lred[32 + row] + Lred[64 + row] + Lred[96 + row];
            O[((size_t)b * L_ + qb + row) * D_ + wave * 16 + l15] = osum / lt;
        }
}

// ------------------------------------------------- fallback (R3, no ws) --
#define KS 72
__global__ __launch_bounds__(NT) void attn_mfma_f16(
    const float* __restrict__ Q, const float* __restrict__ K,
    const float* __restrict__ V, float* __restrict__ O)
{
    __shared__ __align__(16) _Float16 Kt[64 * KS];
    __shared__ __align__(16) _Float16 Vt[D_ * KS];
    __shared__ __align__(16) _Float16 Pt[4][16 * KS];

    const int t = threadIdx.x;
    const int wave = t >> 6, lane = t & 63, quad = lane >> 4, l15 = lane & 15;
    const int bpb = L_ / 64;
    const int b = blockIdx.x / bpb;
    const int qb = (blockIdx.x % bpb) * 64 + wave * 16;
    const size_t boff = (size_t)b * L_ * D_;

    half8_t aq[2];
    {
        const float* qp = Q + boff + (size_t)(qb + l15) * D_ + quad * 8;
        #pragma unroll
        for (int c = 0; c < 2; ++c) {
            const float4* p4 = (const float4*)(qp + c * 32);
            const float4 f0 = p4[0], f1 = p4[1];
            aq[c][0] = (_Float16)f0.x; aq[c][1] = (_Float16)f0.y;
            aq[c][2] = (_Float16)f0.z; aq[c][3] = (_Float16)f0.w;
            aq[c][4] = (_Float16)f1.x; aq[c][5] = (_Float16)f1.y;
            aq[c][6] = (_Float16)f1.z; aq[c][7] = (_Float16)f1.w;
        }
    }
    f32x4 ofr[4];
    #pragma unroll
    for (int d = 0; d < 4; ++d) ofr[d] = (f32x4){0.f, 0.f, 0.f, 0.f};
    float lacc[4] = {0.f, 0.f, 0.f, 0.f};
    const int skey = t & 63, sdg = t >> 6;
    _Float16* Pw = &Pt[wave][0];

    for (int kt = 0; kt < L_ / 64; ++kt) {
        __syncthreads();
        {
            const float4* kg4 = (const float4*)(K + boff + (size_t)(kt * 64 + skey) * D_ + sdg * 16);
            const float4 f0 = kg4[0], f1 = kg4[1], f2 = kg4[2], f3 = kg4[3];
            half8_t w0, w1;
            w0[0] = (_Float16)f0.x; w0[1] = (_Float16)f0.y;
            w0[2] = (_Float16)f0.z; w0[3] = (_Float16)f0.w;
            w0[4] = (_Float16)f1.x; w0[5] = (_Float16)f1.y;
            w0[6] = (_Float16)f1.z; w0[7] = (_Float16)f1.w;
            w1[0] = (_Float16)f2.x; w1[1] = (_Float16)f2.y;
            w1[2] = (_Float16)f2.z; w1[3] = (_Float16)f2.w;
            w1[4] = (_Float16)f3.x; w1[5] = (_Float16)f3.y;
            w1[6] = (_Float16)f3.z; w1[7] = (_Float16)f3.w;
            *(half8_t*)&Kt[skey * KS + sdg * 16] = w0;
            *(half8_t*)&Kt[skey * KS + sdg * 16 + 8] = w1;
        }
        {
            const float4* vg4 = (const float4*)(V + boff + (size_t)(kt * 64 + skey) * D_ + sdg * 16);
            #pragma unroll
            for (int i = 0; i < 4; ++i) {
                const float4 f = vg4[i];
                const int d0 = sdg * 16 + i * 4;
                Vt[(d0 + 0) * KS + skey] = (_Float16)f.x;
                Vt[(d0 + 1) * KS + skey] = (_Float16)f.y;
                Vt[(d0 + 2) * KS + skey] = (_Float16)f.z;
                Vt[(d0 + 3) * KS + skey] = (_Float16)f.w;
            }
        }
        __syncthreads();
        #pragma unroll
        for (int s = 0; s < 4; ++s) {
            const half8_t bk0 = *(const half8_t*)&Kt[(s * 16 + l15) * KS + quad * 8];
            const half8_t bk1 = *(const half8_t*)&Kt[(s * 16 + l15) * KS + 32 + quad * 8];
            f32x4 sc = (f32x4){0.f, 0.f, 0.f, 0.f};
            sc = __builtin_amdgcn_mfma_f32_16x16x32_f16(aq[0], bk0, sc, 0, 0, 0);
            sc = __builtin_amdgcn_mfma_f32_16x16x32_f16(aq[1], bk1, sc, 0, 0, 0);
            #pragma unroll
            for (int r = 0; r < 4; ++r) {
                const float p = __expf(sc[r] * 0.125f);
                lacc[r] += p;
                Pw[(quad * 4 + r) * KS + s * 16 + l15] = (_Float16)p;
            }
        }
        __syncthreads();
        #pragma unroll
        for (int c = 0; c < 2; ++c) {
            const half8_t ap = *(const half8_t*)&Pw[l15 * KS + c * 32 + quad * 8];
            #pragma unroll
            for (int d = 0; d < 4; ++d) {
                const half8_t bv = *(const half8_t*)&Vt[(d * 16 + l15) * KS + c * 32 + quad * 8];
                ofr[d] = __builtin_amdgcn_mfma_f32_16x16x32_f16(ap, bv, ofr[d], 0, 0, 0);
            }
        }
    }
    #pragma unroll
    for (int r = 0; r < 4; ++r) {
        float v = lacc[r];
        v += __shfl_xor(v, 1, 64);
        v += __shfl_xor(v, 2, 64);
        v += __shfl_xor(v, 4, 64);
        v += __shfl_xor(v, 8, 64);
        lacc[r] = v;
    }
    #pragma unroll
    for (int r = 0; r < 4; ++r) {
        const float inv = 1.0f / lacc[r];
        float* orow = O + boff + (size_t)(qb + quad * 4 + r) * D_ + l15;
        #pragma unroll
        for (int d = 0; d < 4; ++d) orow[d * 16] = ofr[d][r] * inv;
    }
}

extern "C" void kernel_launch(void* const* d_in, const int* in_sizes, int n_in,
                              void* d_out, int out_size, void* d_ws, size_t ws_size,
                              hipStream_t stream) {
    const float* Q = (const float*)d_in[0];
    const float* K = (const float*)d_in[1];
    const float* V = (const float*)d_in[2];
    float* O = (float*)d_out;

    if (ws_size >= (size_t)8 * 1024 * 1024) {
        _Float16* K16  = (_Float16*)d_ws;                              // 2 MB
        _Float16* VT16 = K16 + (size_t)B_ * L_ * D_;                   // 2 MB
        prepass<<<768, NT, 0, stream>>>(K, V, K16, VT16);
        attn_bp<<<512, NT, 0, stream>>>(Q, K16, VT16, O);
    } else {
        attn_mfma_f16<<<256, NT, 0, stream>>>(Q, K, V, O);
    }
}

// Round 9
// 92.359 us; speedup vs baseline: 1.0801x; 1.0801x over previous
//
#include <hip/hip_runtime.h>

// ScaledDotProductAttention B=8, L=2048, D=64, fp32 in/out.
//
// Two-launch scheme (ws >= 8 MB):
//  1) prepass: K -> fp16 copy (K16), V -> fp16 transposed (VT16) in d_ws.
//  2) attn_qs4: grid 256 (8 batch x 32 qblocks of 64 queries) -- doubled
//     queries/block vs R7 to HALVE L2 K/V re-read traffic (512->256 MB),
//     which post-R7 analysis says is the binding constraint. 4 waves/block,
//     wave w owns keys [w*512, +512) in 16 tiles of 32 keys.
//     Hot loop has ZERO LDS and ZERO cross-lane ops:
//       - S^T = K*Q^T via mfma_f32_16x16x32_f16 (A=K rows, B=Q rows).
//         C-layout: lane holds S^T[key=kb+ks*16+quad*4+r][q=qs*16+l15].
//       - p = exp2(s) (0.125*log2e folded into Q), packed to half4 -- which
//         IS the B-fragment of mfma_f32_16x16x16f16 (B[k=quad*4+j][n=l15]):
//         PV consumes P^T straight from registers, no transpose at all.
//       - PV: O^T[dim][q] += VT16 half4 A-frags (K=16) x P^T. D-layout:
//         lane holds O^T[dim=d*16+quad*4+r][q=qs*16+l15] -> final store is
//         a per-query float4 (dims quad*4..+4) after l-normalize.
//     l reduced per-lane (4 keys/lane) then shfl over quads; cross-wave
//     (O,l) combine via LDS in a 2-pass epilogue (buffer reuse).
// Fallback: proven R3 kernel if ws too small.

#define B_ 8
#define L_ 2048
#define D_ 64
#define NT 256
#define TK 32              // keys per tile

typedef _Float16 half8_t __attribute__((ext_vector_type(8)));
typedef _Float16 half4_t __attribute__((ext_vector_type(4)));
typedef float f32x4 __attribute__((ext_vector_type(4)));

#define SCALE_LOG2E 0.1803368801111244f   // 0.125 * log2(e)

// ---------------------------------------------------------------- prepass --
// blocks 0..511: K cast; 512..767: V transpose.
__global__ __launch_bounds__(NT) void prepass(
    const float* __restrict__ K, const float* __restrict__ V,
    _Float16* __restrict__ K16, _Float16* __restrict__ VT16)
{
    const int blk = blockIdx.x;
    const int t = threadIdx.x;
    if (blk < 512) {
        const int i = blk * NT + t;                  // half8 index, 131072 total
        const float4* s4 = (const float4*)K;
        const float4 a = s4[2 * i], b = s4[2 * i + 1];
        half8_t w;
        w[0] = (_Float16)a.x; w[1] = (_Float16)a.y;
        w[2] = (_Float16)a.z; w[3] = (_Float16)a.w;
        w[4] = (_Float16)b.x; w[5] = (_Float16)b.y;
        w[6] = (_Float16)b.z; w[7] = (_Float16)b.w;
        ((half8_t*)K16)[i] = w;
    } else {
        __shared__ __align__(16) _Float16 Lt[64 * 72];   // [dim][key] tile
        const int vblk = blk - 512;
        const int bb = vblk >> 5;            // batch
        const int kt = vblk & 31;            // 64-key tile
        const int r  = t >> 2;               // key row 0..63
        const int ch = t & 3;                // 16-dim chunk
        const float* vrow = V + ((size_t)bb * L_ + kt * 64 + r) * D_ + ch * 16;
        #pragma unroll
        for (int i = 0; i < 4; ++i) {
            const float4 f = ((const float4*)vrow)[i];
            const int d0 = ch * 16 + i * 4;
            Lt[(d0 + 0) * 72 + r] = (_Float16)f.x;
            Lt[(d0 + 1) * 72 + r] = (_Float16)f.y;
            Lt[(d0 + 2) * 72 + r] = (_Float16)f.z;
            Lt[(d0 + 3) * 72 + r] = (_Float16)f.w;
        }
        __syncthreads();
        const int d  = t >> 2;               // dim row 0..63
        const int c2 = t & 3;                // 16-key chunk
        const half8_t w0 = *(const half8_t*)&Lt[d * 72 + c2 * 16];
        const half8_t w1 = *(const half8_t*)&Lt[d * 72 + c2 * 16 + 8];
        _Float16* orow = VT16 + ((size_t)bb * D_ + d) * L_ + kt * 64 + c2 * 16;
        *(half8_t*)orow = w0;
        *(half8_t*)(orow + 8) = w1;
    }
}

// -------------------------------------------------------------- main body --

// Load K B-row fragments for the 32-key tile at KB.
#define LOADK(KB, BK)                                                           \
    {                                                                           \
        _Pragma("unroll") for (int s = 0; s < 2; ++s)                           \
        _Pragma("unroll") for (int c = 0; c < 2; ++c)                           \
            BK[s][c] = *(const half8_t*)&Kb[(size_t)((KB) + s * 16 + l15) * D_ + c * 32 + quad * 8]; \
    }

// Process one 32-key tile at KB using K frags BK.
#define PROC(KB, BK)                                                            \
    {                                                                           \
        half4_t av[4][2];                                                       \
        _Pragma("unroll") for (int d = 0; d < 4; ++d)                           \
        _Pragma("unroll") for (int ks = 0; ks < 2; ++ks)                        \
            av[d][ks] = *(const half4_t*)&Vb[(size_t)(d * 16 + l15) * L_ + (KB) + ks * 16 + quad * 4]; \
        f32x4 sc[2][4];                                                         \
        _Pragma("unroll") for (int ks = 0; ks < 2; ++ks)                        \
        _Pragma("unroll") for (int qs = 0; qs < 4; ++qs) {                      \
            f32x4 acc = (f32x4){0.f, 0.f, 0.f, 0.f};                            \
            acc = __builtin_amdgcn_mfma_f32_16x16x32_f16(BK[ks][0], bq[qs][0], acc, 0, 0, 0); \
            acc = __builtin_amdgcn_mfma_f32_16x16x32_f16(BK[ks][1], bq[qs][1], acc, 0, 0, 0); \
            sc[ks][qs] = acc;                                                   \
        }                                                                       \
        half4_t pb[2][4];                                                       \
        _Pragma("unroll") for (int ks = 0; ks < 2; ++ks)                        \
        _Pragma("unroll") for (int qs = 0; qs < 4; ++qs) {                      \
            const float p0 = __builtin_exp2f(sc[ks][qs][0]);                    \
            const float p1 = __builtin_exp2f(sc[ks][qs][1]);                    \
            const float p2 = __builtin_exp2f(sc[ks][qs][2]);                    \
            const float p3 = __builtin_exp2f(sc[ks][qs][3]);                    \
            lacc[qs] += (p0 + p1) + (p2 + p3);                                  \
            half4_t pv;                                                         \
            pv[0] = (_Float16)p0; pv[1] = (_Float16)p1;                         \
            pv[2] = (_Float16)p2; pv[3] = (_Float16)p3;                         \
            pb[ks][qs] = pv;                                                    \
        }                                                                       \
        _Pragma("unroll") for (int qs = 0; qs < 4; ++qs)                        \
        _Pragma("unroll") for (int d = 0; d < 4; ++d)                           \
        _Pragma("unroll") for (int ks = 0; ks < 2; ++ks)                        \
            ofr[qs][d] = __builtin_amdgcn_mfma_f32_16x16x16f16(av[d][ks], pb[ks][qs], ofr[qs][d], 0, 0, 0); \
    }

__global__ __launch_bounds__(NT) void attn_qs4(
    const float* __restrict__ Q,
    const _Float16* __restrict__ K16,
    const _Float16* __restrict__ VT16,
    float* __restrict__ O)
{
    __shared__ float Ored[256 * 33];                     // 33792 B (epilogue only)
    __shared__ float Lred[256];                          // 1 KB

    const int t    = threadIdx.x;
    const int wave = t >> 6;
    const int lane = t & 63;
    const int quad = lane >> 4;
    const int l15  = lane & 15;

    const int b   = blockIdx.x & 7;            // batch <-> XCD affinity
    const int qbi = blockIdx.x >> 3;           // query block 0..31
    const int qb  = qbi * 64;
    const int key0 = wave * (TK * 16);         // wave's 512-key range

    const _Float16* Kb = K16 + (size_t)b * L_ * D_;
    const _Float16* Vb = VT16 + (size_t)b * D_ * L_;

    // ---- Q B-frags from fp32, pre-scaled by 0.125*log2(e) ----
    half8_t bq[4][2];
    #pragma unroll
    for (int qs = 0; qs < 4; ++qs) {
        const float* qp = Q + ((size_t)b * L_ + qb + qs * 16 + l15) * D_ + quad * 8;
        #pragma unroll
        for (int c = 0; c < 2; ++c) {
            const float4 f0 = *(const float4*)(qp + c * 32);
            const float4 f1 = *(const float4*)(qp + c * 32 + 4);
            bq[qs][c][0] = (_Float16)(f0.x * SCALE_LOG2E);
            bq[qs][c][1] = (_Float16)(f0.y * SCALE_LOG2E);
            bq[qs][c][2] = (_Float16)(f0.z * SCALE_LOG2E);
            bq[qs][c][3] = (_Float16)(f0.w * SCALE_LOG2E);
            bq[qs][c][4] = (_Float16)(f1.x * SCALE_LOG2E);
            bq[qs][c][5] = (_Float16)(f1.y * SCALE_LOG2E);
            bq[qs][c][6] = (_Float16)(f1.z * SCALE_LOG2E);
            bq[qs][c][7] = (_Float16)(f1.w * SCALE_LOG2E);
        }
    }

    f32x4 ofr[4][4];
    #pragma unroll
    for (int qs = 0; qs < 4; ++qs)
        #pragma unroll
        for (int d = 0; d < 4; ++d)
            ofr[qs][d] = (f32x4){0.f, 0.f, 0.f, 0.f};
    float lacc[4] = {0.f, 0.f, 0.f, 0.f};

    // ---- hot loop: 16 tiles of 32 keys, K frags double-buffered ----
    half8_t bkA[2][2], bkB[2][2];
    LOADK(key0, bkA);
    for (int it = 0; it < 8; ++it) {
        const int kb = key0 + it * 64;
        LOADK(kb + 32, bkB);
        PROC(kb, bkA);
        // final prefetch overruns the wave's range by 32 keys; stays inside
        // the ws mapping (K16 is followed by VT16) and is never consumed.
        LOADK(kb + 64, bkA);
        PROC(kb + 32, bkB);
    }

    // ---- l: reduce over quads (each lane holds 4 keys of query qs*16+l15) --
    #pragma unroll
    for (int qs = 0; qs < 4; ++qs) {
        float v = lacc[qs];
        v += __shfl_xor(v, 16, 64);
        v += __shfl_xor(v, 32, 64);
        lacc[qs] = v;
    }
    if (quad == 0) {
        #pragma unroll
        for (int qs = 0; qs < 4; ++qs)
            Lred[wave * 64 + qs * 16 + l15] = lacc[qs];
    }

    // ---- cross-wave combine, 2 passes over the shared buffer ----
    #pragma unroll
    for (int pass = 0; pass < 2; ++pass) {
        __syncthreads();
        #pragma unroll
        for (int qh = 0; qh < 2; ++qh) {
            const int qs = pass * 2 + qh;
            #pragma unroll
            for (int d = 0; d < 4; ++d)
                #pragma unroll
                for (int r = 0; r < 4; ++r)
                    Ored[(wave * 64 + lane) * 33 + qh * 16 + d * 4 + r] = ofr[qs][d][r];
        }
        __syncthreads();
        #pragma unroll
        for (int qh = 0; qh < 2; ++qh) {
            const int qs = pass * 2 + qh;
            const float lt = Lred[qs * 16 + l15] + Lred[64 + qs * 16 + l15]
                           + Lred[128 + qs * 16 + l15] + Lred[192 + qs * 16 + l15];
            const float inv = 1.0f / lt;
            f32x4 osum = (f32x4){0.f, 0.f, 0.f, 0.f};
            #pragma unroll
            for (int w2 = 0; w2 < 4; ++w2) {
                const float* src = &Ored[(w2 * 64 + lane) * 33 + qh * 16 + wave * 4];
                osum[0] += src[0]; osum[1] += src[1];
                osum[2] += src[2]; osum[3] += src[3];
            }
            float4 outv;
            outv.x = osum[0] * inv; outv.y = osum[1] * inv;
            outv.z = osum[2] * inv; outv.w = osum[3] * inv;
            // dim = wave*16 + quad*4 + r ; query = qb + qs*16 + l15
            *(float4*)&O[((size_t)b * L_ + qb + qs * 16 + l15) * D_ + wave * 16 + quad * 4] = outv;
        }
    }
}

// ------------------------------------------------- fallback (R3, no ws) --
#define KS 72
__global__ __launch_bounds__(NT) void attn_mfma_f16(
    const float* __restrict__ Q, const float* __restrict__ K,
    const float* __restrict__ V, float* __restrict__ O)
{
    __shared__ __align__(16) _Float16 Kt[64 * KS];
    __shared__ __align__(16) _Float16 Vt[D_ * KS];
    __shared__ __align__(16) _Float16 Pt[4][16 * KS];

    const int t = threadIdx.x;
    const int wave = t >> 6, lane = t & 63, quad = lane >> 4, l15 = lane & 15;
    const int bpb = L_ / 64;
    const int b = blockIdx.x / bpb;
    const int qb = (blockIdx.x % bpb) * 64 + wave * 16;
    const size_t boff = (size_t)b * L_ * D_;

    half8_t aq[2];
    {
        const float* qp = Q + boff + (size_t)(qb + l15) * D_ + quad * 8;
        #pragma unroll
        for (int c = 0; c < 2; ++c) {
            const float4* p4 = (const float4*)(qp + c * 32);
            const float4 f0 = p4[0], f1 = p4[1];
            aq[c][0] = (_Float16)f0.x; aq[c][1] = (_Float16)f0.y;
            aq[c][2] = (_Float16)f0.z; aq[c][3] = (_Float16)f0.w;
            aq[c][4] = (_Float16)f1.x; aq[c][5] = (_Float16)f1.y;
            aq[c][6] = (_Float16)f1.z; aq[c][7] = (_Float16)f1.w;
        }
    }
    f32x4 ofr[4];
    #pragma unroll
    for (int d = 0; d < 4; ++d) ofr[d] = (f32x4){0.f, 0.f, 0.f, 0.f};
    float lacc[4] = {0.f, 0.f, 0.f, 0.f};
    const int skey = t & 63, sdg = t >> 6;
    _Float16* Pw = &Pt[wave][0];

    for (int kt = 0; kt < L_ / 64; ++kt) {
        __syncthreads();
        {
            const float4* kg4 = (const float4*)(K + boff + (size_t)(kt * 64 + skey) * D_ + sdg * 16);
            const float4 f0 = kg4[0], f1 = kg4[1], f2 = kg4[2], f3 = kg4[3];
            half8_t w0, w1;
            w0[0] = (_Float16)f0.x; w0[1] = (_Float16)f0.y;
            w0[2] = (_Float16)f0.z; w0[3] = (_Float16)f0.w;
            w0[4] = (_Float16)f1.x; w0[5] = (_Float16)f1.y;
            w0[6] = (_Float16)f1.z; w0[7] = (_Float16)f1.w;
            w1[0] = (_Float16)f2.x; w1[1] = (_Float16)f2.y;
            w1[2] = (_Float16)f2.z; w1[3] = (_Float16)f2.w;
            w1[4] = (_Float16)f3.x; w1[5] = (_Float16)f3.y;
            w1[6] = (_Float16)f3.z; w1[7] = (_Float16)f3.w;
            *(half8_t*)&Kt[skey * KS + sdg * 16] = w0;
            *(half8_t*)&Kt[skey * KS + sdg * 16 + 8] = w1;
        }
        {
            const float4* vg4 = (const float4*)(V + boff + (size_t)(kt * 64 + skey) * D_ + sdg * 16);
            #pragma unroll
            for (int i = 0; i < 4; ++i) {
                const float4 f = vg4[i];
                const int d0 = sdg * 16 + i * 4;
                Vt[(d0 + 0) * KS + skey] = (_Float16)f.x;
                Vt[(d0 + 1) * KS + skey] = (_Float16)f.y;
                Vt[(d0 + 2) * KS + skey] = (_Float16)f.z;
                Vt[(d0 + 3) * KS + skey] = (_Float16)f.w;
            }
        }
        __syncthreads();
        #pragma unroll
        for (int s = 0; s < 4; ++s) {
            const half8_t bk0 = *(const half8_t*)&Kt[(s * 16 + l15) * KS + quad * 8];
            const half8_t bk1 = *(const half8_t*)&Kt[(s * 16 + l15) * KS + 32 + quad * 8];
            f32x4 sc = (f32x4){0.f, 0.f, 0.f, 0.f};
            sc = __builtin_amdgcn_mfma_f32_16x16x32_f16(aq[0], bk0, sc, 0, 0, 0);
            sc = __builtin_amdgcn_mfma_f32_16x16x32_f16(aq[1], bk1, sc, 0, 0, 0);
            #pragma unroll
            for (int r = 0; r < 4; ++r) {
                const float p = __expf(sc[r] * 0.125f);
                lacc[r] += p;
                Pw[(quad * 4 + r) * KS + s * 16 + l15] = (_Float16)p;
            }
        }
        __syncthreads();
        #pragma unroll
        for (int c = 0; c < 2; ++c) {
            const half8_t ap = *(const half8_t*)&Pw[l15 * KS + c * 32 + quad * 8];
            #pragma unroll
            for (int d = 0; d < 4; ++d) {
                const half8_t bv = *(const half8_t*)&Vt[(d * 16 + l15) * KS + c * 32 + quad * 8];
                ofr[d] = __builtin_amdgcn_mfma_f32_16x16x32_f16(ap, bv, ofr[d], 0, 0, 0);
            }
        }
    }
    #pragma unroll
    for (int r = 0; r < 4; ++r) {
        float v = lacc[r];
        v += __shfl_xor(v, 1, 64);
        v += __shfl_xor(v, 2, 64);
        v += __shfl_xor(v, 4, 64);
        v += __shfl_xor(v, 8, 64);
        lacc[r] = v;
    }
    #pragma unroll
    for (int r = 0; r < 4; ++r) {
        const float inv = 1.0f / lacc[r];
        float* orow = O + boff + (size_t)(qb + quad * 4 + r) * D_ + l15;
        #pragma unroll
        for (int d = 0; d < 4; ++d) orow[d * 16] = ofr[d][r] * inv;
    }
}

extern "C" void kernel_launch(void* const* d_in, const int* in_sizes, int n_in,
                              void* d_out, int out_size, void* d_ws, size_t ws_size,
                              hipStream_t stream) {
    const float* Q = (const float*)d_in[0];
    const float* K = (const float*)d_in[1];
    const float* V = (const float*)d_in[2];
    float* O = (float*)d_out;

    if (ws_size >= (size_t)8 * 1024 * 1024) {
        _Float16* K16  = (_Float16*)d_ws;                              // 2 MB
        _Float16* VT16 = K16 + (size_t)B_ * L_ * D_;                   // 2 MB
        prepass<<<768, NT, 0, stream>>>(K, V, K16, VT16);
        attn_qs4<<<256, NT, 0, stream>>>(Q, K16, VT16, O);
    } else {
        attn_mfma_f16<<<256, NT, 0, stream>>>(Q, K, V, O);
    }
}